// Round 1
// baseline (692.652 us; speedup 1.0000x reference)
//
#include <hip/hip_runtime.h>

// Deformable depthwise 3x3 conv, B=8 C=256 H=W=96, fp32.
// R5: LSTR=96 (bank = xc%32, row-jitter-invariant), full-plane LDS. 166 us.
//     Counters: VALUBusy 20%, Occ 35%, VGPR=40 (!) -> cw[9][4]+lofs[9] ~50
//     live values cannot fit: compiler spills cw to scratch, reloading ~36
//     values per channel on the gather critical path. Also __syncthreads()
//     drains vmcnt(0) -> the R5 "prefetch" dies at the barrier it should
//     have crossed. Everything idle == stall-bound.
// R6: (a) __launch_bounds__(NT,6): VGPR cap 85, kill the spill.
//     (b) True double-buffer, CAP=24 rows/buffer (18.4 KB total LDS),
//         ONE barrier per channel: gather(buf p) | write(buf p^1) | issue
//         prefetch 2 channels ahead (pfA=odd->buf1, pfB=even->buf0).
//     (c) Raw "s_waitcnt lgkmcnt(0); s_barrier" -- LDS-write visibility
//         only, prefetch loads stay in flight ACROSS barriers (counted-
//         vmcnt idiom); compiler inserts the precise vmcnt at consumption.
//     (d) float2 tap reads -> ds_read2_b32: 36 -> 18 LDS instr/pix/chan.
//     (e) nrows > 24 (never on N(0,1) offsets): uniform direct-global
//         fallback path, no barriers, still exact.

constexpr int B_ = 8, C_ = 256, H_ = 96, W_ = 96;
constexpr int HW_ = H_ * W_;
constexpr int TH = 4;              // pixel rows per block
constexpr int NT = TH * W_;        // 384 threads = 6 waves
constexpr int CSPLIT = 8;
constexpr int CPB = C_ / CSPLIT;   // 32 channels per block
constexpr int CAP = 24;            // window rows per buffer (typ. ~15 used)
constexpr int CAPE = CAP * W_;     // 2304 floats = 9216 B per buffer

// Workgroup barrier that does NOT drain vmcnt: LDS writes made visible
// (lgkmcnt(0)), global prefetch loads stay in flight across the barrier.
#define WGBAR() asm volatile("s_waitcnt lgkmcnt(0)\n\ts_barrier" ::: "memory")

__global__ __launch_bounds__(NT, 6) void deform_dw_conv(
    const float* __restrict__ x, const float* __restrict__ off,
    const float* __restrict__ wgt, const float* __restrict__ bias,
    float* __restrict__ out)
{
    __shared__ float lx[2 * CAPE];   // double buffer, dense 96-dword rows
    __shared__ int s_rmin, s_rmax;

    const int tid  = threadIdx.x;
    const int r    = tid / W_;
    const int wcol = tid - r * W_;
    const int h    = blockIdx.x * TH + r;
    const int b    = blockIdx.y;
    const int c0   = blockIdx.z * CPB;

    if (tid == 0) { s_rmin = H_; s_rmax = -1; }
    __syncthreads();

    const float* offp = off + (size_t)b * 18 * HW_ + (size_t)h * W_ + wcol;

    // Per-(pixel,tap): 4 weights pre-permuted onto loaded positions
    // [0]=(yc,xc) [1]=(yc,xc+1) [2]=(yc+1,xc) [3]=(yc+1,xc+1); validity
    // folded into weights so invalid corners multiply by 0.
    float cw[9][4];
    int lofs[9];                     // absolute plane offset yc*96+xc
    int myrmin = H_, myrmax = -1;

#pragma unroll
    for (int kk = 0; kk < 9; ++kk) {
        const int i = kk / 3, j = kk % 3;
        const float py = (float)(h - 1 + i) + offp[(2 * kk) * HW_];
        const float px = (float)(wcol - 1 + j) + offp[(2 * kk + 1) * HW_];
        const float fy = floorf(py), fx = floorf(px);
        const float wy = py - fy, wx = px - fx;
        const int y0 = (int)fy, x0 = (int)fx;
        const bool vy0 = (unsigned)y0 < (unsigned)H_;
        const bool vy1 = (unsigned)(y0 + 1) < (unsigned)H_;
        const bool vx0 = (unsigned)x0 < (unsigned)W_;
        const bool vx1 = (unsigned)(x0 + 1) < (unsigned)W_;
        const float w00 = (vy0 && vx0) ? (1.f - wy) * (1.f - wx) : 0.f;
        const float w01 = (vy0 && vx1) ? (1.f - wy) * wx : 0.f;
        const float w10 = (vy1 && vx0) ? wy * (1.f - wx) : 0.f;
        const float w11 = (vy1 && vx1) ? wy * wx : 0.f;
        const int yc = min(max(y0, 0), H_ - 2);
        const int xc = min(max(x0, 0), W_ - 2);
        const bool rs = (y0 == yc);
        const bool cs = (x0 == xc);
        cw[kk][0] = rs ? (cs ? w00 : w01) : (cs ? w10 : w11);
        cw[kk][1] = rs ? (cs ? w01 : w00) : (cs ? w11 : w10);
        cw[kk][2] = rs ? (cs ? w10 : w11) : (cs ? w00 : w01);
        cw[kk][3] = rs ? (cs ? w11 : w10) : (cs ? w01 : w00);
        lofs[kk] = yc * W_ + xc;
        myrmin = min(myrmin, yc);
        myrmax = max(myrmax, yc);
    }
    atomicMin(&s_rmin, myrmin);
    atomicMax(&s_rmax, myrmax);
    __syncthreads();
    const int rmin  = s_rmin;
    const int nrows = s_rmax + 2 - rmin;   // rows [rmin, rmax+1]
    const int pix   = h * W_ + wcol;

    if (nrows > CAP) {
        // Cold correctness path: direct global gather (clamped coords are
        // always in-bounds; zero weights neutralize invalid corners).
        // Uniform per block; no barriers from here on.
        const float* xp = x + (size_t)(b * C_ + c0) * HW_;
        float* op = out + (size_t)(b * C_ + c0) * HW_ + pix;
        for (int cc = 0; cc < CPB; ++cc) {
            float acc = 0.f;
#pragma unroll
            for (int kk = 0; kk < 9; ++kk) {
                const float* q = xp + lofs[kk];
                float s = cw[kk][0] * q[0];
                s = fmaf(cw[kk][1], q[1], s);
                s = fmaf(cw[kk][2], q[W_], s);
                s = fmaf(cw[kk][3], q[W_ + 1], s);
                acc = fmaf(wgt[(c0 + cc) * 9 + kk], s, acc);
            }
            *op = acc + bias[c0 + cc];
            xp += HW_; op += HW_;
        }
        return;
    }

#pragma unroll
    for (int kk = 0; kk < 9; ++kk) lofs[kk] -= rmin * W_;

    // Staging: window is dense in both global (row-major) and LDS
    // (stride 96 == W), so it is a straight contiguous float2 copy.
    const int n2 = nrows * (W_ / 2);             // <= 3*NT by CAP=24
    const int t0 = tid, t1 = tid + NT, t2 = tid + 2 * NT;

    const float* xwin = x + (size_t)(b * C_ + c0) * HW_ + rmin * W_;

    // stage channel c0 -> buf0 directly
    {
        const float2* s2 = (const float2*)xwin;
        if (t0 < n2) *(float2*)&lx[2 * t0] = s2[t0];
        if (t1 < n2) *(float2*)&lx[2 * t1] = s2[t1];
        if (t2 < n2) *(float2*)&lx[2 * t2] = s2[t2];
    }
    // prefetch c0+1 (pfA, lands in buf1) and c0+2 (pfB, lands in buf0)
    float2 pa0{}, pa1{}, pa2{}, pb0{}, pb1{}, pb2{};
    {
        const float2* s2 = (const float2*)(xwin + HW_);
        if (t0 < n2) pa0 = s2[t0];
        if (t1 < n2) pa1 = s2[t1];
        if (t2 < n2) pa2 = s2[t2];
    }
    {
        const float2* s2 = (const float2*)(xwin + 2 * (size_t)HW_);
        if (t0 < n2) pb0 = s2[t0];
        if (t1 < n2) pb1 = s2[t1];
        if (t2 < n2) pb2 = s2[t2];
    }
    const float* xA = xwin + 3 * (size_t)HW_;    // next odd-channel window
    const float* xB = xwin + 4 * (size_t)HW_;    // next even-channel window
    WGBAR();

    float* outp = out + (size_t)(b * C_ + c0) * HW_ + pix;
    const float* wp = wgt + c0 * 9;
    const float* bp = bias + c0;

#pragma unroll 1
    for (int e = 0; e < CPB; e += 2) {
        // ---- body A: channel c0+e from buf0; write pfA -> buf1 ----
        {
            float acc = 0.f;
#pragma unroll
            for (int kk = 0; kk < 9; ++kk) {
                float2 A, Bv;                      // ds_read2_b32 pairs
                __builtin_memcpy(&A,  &lx[lofs[kk]],       sizeof(float2));
                __builtin_memcpy(&Bv, &lx[lofs[kk] + W_],  sizeof(float2));
                float s = cw[kk][0] * A.x;
                s = fmaf(cw[kk][1], A.y,  s);
                s = fmaf(cw[kk][2], Bv.x, s);
                s = fmaf(cw[kk][3], Bv.y, s);
                acc = fmaf(wp[e * 9 + kk], s, acc);
            }
            *outp = acc + bp[e];
            outp += HW_;
            // channel e+1 into buf1 (vmcnt wait lands here, ~2 phases deep)
            if (t0 < n2) *(float2*)&lx[CAPE + 2 * t0] = pa0;
            if (t1 < n2) *(float2*)&lx[CAPE + 2 * t1] = pa1;
            if (t2 < n2) *(float2*)&lx[CAPE + 2 * t2] = pa2;
            if (e + 3 < CPB) {                     // issue pfA = channel e+3
                const float2* s2 = (const float2*)xA;
                if (t0 < n2) pa0 = s2[t0];
                if (t1 < n2) pa1 = s2[t1];
                if (t2 < n2) pa2 = s2[t2];
                xA += 2 * (size_t)HW_;
            }
            WGBAR();
        }
        // ---- body B: channel c0+e+1 from buf1; write pfB -> buf0 ----
        {
            float acc = 0.f;
#pragma unroll
            for (int kk = 0; kk < 9; ++kk) {
                float2 A, Bv;
                __builtin_memcpy(&A,  &lx[CAPE + lofs[kk]],      sizeof(float2));
                __builtin_memcpy(&Bv, &lx[CAPE + lofs[kk] + W_], sizeof(float2));
                float s = cw[kk][0] * A.x;
                s = fmaf(cw[kk][1], A.y,  s);
                s = fmaf(cw[kk][2], Bv.x, s);
                s = fmaf(cw[kk][3], Bv.y, s);
                acc = fmaf(wp[(e + 1) * 9 + kk], s, acc);
            }
            *outp = acc + bp[e + 1];
            outp += HW_;
            if (e + 2 < CPB) {
                // channel e+2 into buf0
                if (t0 < n2) *(float2*)&lx[2 * t0] = pb0;
                if (t1 < n2) *(float2*)&lx[2 * t1] = pb1;
                if (t2 < n2) *(float2*)&lx[2 * t2] = pb2;
                if (e + 4 < CPB) {                 // issue pfB = channel e+4
                    const float2* s2 = (const float2*)xB;
                    if (t0 < n2) pb0 = s2[t0];
                    if (t1 < n2) pb1 = s2[t1];
                    if (t2 < n2) pb2 = s2[t2];
                    xB += 2 * (size_t)HW_;
                }
                WGBAR();
            }
        }
    }
}

extern "C" void kernel_launch(void* const* d_in, const int* in_sizes, int n_in,
                              void* d_out, int out_size, void* d_ws, size_t ws_size,
                              hipStream_t stream) {
    const float* x    = (const float*)d_in[0];
    const float* off  = (const float*)d_in[1];
    const float* w    = (const float*)d_in[2];
    const float* bias = (const float*)d_in[3];
    float* out        = (float*)d_out;
    dim3 grid(H_ / TH, B_, CSPLIT);
    deform_dw_conv<<<grid, NT, 0, stream>>>(x, off, w, bias, out);
}

// Round 2
// 276.743 us; speedup vs baseline: 2.5029x; 2.5029x over previous
//
#include <hip/hip_runtime.h>

// Deformable depthwise 3x3 conv, B=8 C=256 H=W=96, fp32.
// R5: LSTR=96 full-plane LDS, 2 barriers/chan, reg prefetch killed by
//     __syncthreads vmcnt drain. 166 us. VGPR=40 + AGPR overflow (unified
//     file) -> combined ~104 regs -> 2 blocks/CU (Occ 35%).
// R6: REGRESSED 604 us. __launch_bounds__(NT,6) capped COMBINED VGPR+AGPR
//     at ~85; +12 prefetch regs pushed overflow from AGPRs into scratch
//     MEMORY: FETCH +490MB, WRITE +330MB of spill traffic. Lesson: on
//     gfx950 min-waves bounds turn free AGPR spill into HBM scratch spill.
// R7: register-free async staging via global_load_lds (width 16):
//     - window rows are dense (LDS stride == W == 96) -> exactly the
//       linear wave-ordered layout gload_lds writes; zero data VGPRs.
//     - double buffer CAP=24 rows (18.4 KB), ONE __syncthreads per
//       channel: issue next-channel gload_lds -> compute current ->
//       barrier (its vmcnt(0) drain IS the wait, after compute).
//     - __launch_bounds__(NT,4): cap 128 combined, roomy -> no scratch.
//     - bank = xc%32 (96 % 32 == 0), row-jitter-invariant as in R5.

constexpr int B_ = 8, C_ = 256, H_ = 96, W_ = 96;
constexpr int HW_ = H_ * W_;
constexpr int TH = 4;              // pixel rows per block
constexpr int NT = TH * W_;        // 384 threads = 6 waves
constexpr int CSPLIT = 8;
constexpr int CPB = C_ / CSPLIT;   // 32 channels per block
constexpr int CAP = 24;            // window rows per buffer (typ. ~15 used)
constexpr int CAPE = CAP * W_;     // 2304 floats = 9216 B per buffer

__device__ __forceinline__ void gl_lds16(const float* g, float* l) {
    // async global->LDS, 16B per lane; LDS dest = wave-uniform base +
    // lane*16 which matches our linear chunk layout exactly.
    __builtin_amdgcn_global_load_lds(
        (const __attribute__((address_space(1))) void*)g,
        (__attribute__((address_space(3))) void*)l, 16, 0, 0);
}

__global__ __launch_bounds__(NT, 4) void deform_dw_conv(
    const float* __restrict__ x, const float* __restrict__ off,
    const float* __restrict__ wgt, const float* __restrict__ bias,
    float* __restrict__ out)
{
    __shared__ float lx[2 * CAPE];   // double buffer, dense 96-dword rows
    __shared__ int s_rmin, s_rmax;

    const int tid  = threadIdx.x;
    const int r    = tid / W_;
    const int wcol = tid - r * W_;
    const int h    = blockIdx.x * TH + r;
    const int b    = blockIdx.y;
    const int c0   = blockIdx.z * CPB;

    if (tid == 0) { s_rmin = H_; s_rmax = -1; }
    __syncthreads();

    const float* offp = off + (size_t)b * 18 * HW_ + (size_t)h * W_ + wcol;

    // Per-(pixel,tap): 4 weights pre-permuted onto loaded positions
    // [0]=(yc,xc) [1]=(yc,xc+1) [2]=(yc+1,xc) [3]=(yc+1,xc+1); validity
    // folded into weights so invalid corners multiply by 0.
    float cw[9][4];
    int lofs[9];                     // plane offset yc*96+xc (abs for now)
    int myrmin = H_, myrmax = -1;

#pragma unroll
    for (int kk = 0; kk < 9; ++kk) {
        const int i = kk / 3, j = kk % 3;
        const float py = (float)(h - 1 + i) + offp[(2 * kk) * HW_];
        const float px = (float)(wcol - 1 + j) + offp[(2 * kk + 1) * HW_];
        const float fy = floorf(py), fx = floorf(px);
        const float wy = py - fy, wx = px - fx;
        const int y0 = (int)fy, x0 = (int)fx;
        const bool vy0 = (unsigned)y0 < (unsigned)H_;
        const bool vy1 = (unsigned)(y0 + 1) < (unsigned)H_;
        const bool vx0 = (unsigned)x0 < (unsigned)W_;
        const bool vx1 = (unsigned)(x0 + 1) < (unsigned)W_;
        const float w00 = (vy0 && vx0) ? (1.f - wy) * (1.f - wx) : 0.f;
        const float w01 = (vy0 && vx1) ? (1.f - wy) * wx : 0.f;
        const float w10 = (vy1 && vx0) ? wy * (1.f - wx) : 0.f;
        const float w11 = (vy1 && vx1) ? wy * wx : 0.f;
        const int yc = min(max(y0, 0), H_ - 2);
        const int xc = min(max(x0, 0), W_ - 2);
        const bool rs = (y0 == yc);
        const bool cs = (x0 == xc);
        cw[kk][0] = rs ? (cs ? w00 : w01) : (cs ? w10 : w11);
        cw[kk][1] = rs ? (cs ? w01 : w00) : (cs ? w11 : w10);
        cw[kk][2] = rs ? (cs ? w10 : w11) : (cs ? w00 : w01);
        cw[kk][3] = rs ? (cs ? w11 : w10) : (cs ? w01 : w00);
        lofs[kk] = yc * W_ + xc;
        myrmin = min(myrmin, yc);
        myrmax = max(myrmax, yc);
    }
    atomicMin(&s_rmin, myrmin);
    atomicMax(&s_rmax, myrmax);
    __syncthreads();
    const int rmin  = s_rmin;
    const int nrows = s_rmax + 2 - rmin;   // rows [rmin, rmax+1]
    const int pix   = h * W_ + wcol;

    if (nrows > CAP) {
        // Cold correctness path (never on N(0,1) offsets): direct global
        // gather; clamped coords always in-bounds, zero weights neutralize
        // invalid corners. Block-uniform branch; no barriers after this.
        const float* xp = x + (size_t)(b * C_ + c0) * HW_;
        float* op = out + (size_t)(b * C_ + c0) * HW_ + pix;
        for (int cc = 0; cc < CPB; ++cc) {
            float acc = 0.f;
#pragma unroll
            for (int kk = 0; kk < 9; ++kk) {
                const float* q = xp + lofs[kk];
                float s = cw[kk][0] * q[0];
                s = fmaf(cw[kk][1], q[1], s);
                s = fmaf(cw[kk][2], q[W_], s);
                s = fmaf(cw[kk][3], q[W_ + 1], s);
                acc = fmaf(wgt[(c0 + cc) * 9 + kk], s, acc);
            }
            *op = acc + bias[c0 + cc];
            xp += HW_; op += HW_;
        }
        return;
    }

#pragma unroll
    for (int kk = 0; kk < 9; ++kk) lofs[kk] -= rmin * W_;

    // Staging geometry: n4 float4 chunks, linear in both global and LDS.
    // n4 <= CAP*24 = 576 <= 2*NT, so two predicated calls cover it.
    const int n4 = nrows * (W_ / 4);
    const int t0 = tid, t1 = tid + NT;

    const float* xwin = x + (size_t)(b * C_ + c0) * HW_ + rmin * W_;

    // stage channel c0 -> buf0 (async), barrier drains vmcnt -> ready
    if (t0 < n4) gl_lds16(xwin + 4 * t0, &lx[4 * t0]);
    if (t1 < n4) gl_lds16(xwin + 4 * t1, &lx[4 * t1]);
    __syncthreads();

    float* outp = out + (size_t)(b * C_ + c0) * HW_ + pix;
    const float* wp = wgt + c0 * 9;
    const float* bp = bias + c0;

    int pb = 0;                       // current read buffer (float offset)
#pragma unroll 1
    for (int cc = 0; cc < CPB; ++cc) {
        // Issue next channel's async staging into the other buffer BEFORE
        // compute; the wait is the vmcnt(0) inside the barrier below,
        // i.e. fully hidden under this channel's gather.
        if (cc + 1 < CPB) {
            const float* nxt = xwin + (size_t)(cc + 1) * HW_;
            const int ob = pb ^ CAPE;
            if (t0 < n4) gl_lds16(nxt + 4 * t0, &lx[ob + 4 * t0]);
            if (t1 < n4) gl_lds16(nxt + 4 * t1, &lx[ob + 4 * t1]);
        }

        float acc = 0.f;
#pragma unroll
        for (int kk = 0; kk < 9; ++kk) {
            float2 A, Bv;                       // ds_read2_b32 pairs
            __builtin_memcpy(&A,  &lx[pb + lofs[kk]],      sizeof(float2));
            __builtin_memcpy(&Bv, &lx[pb + lofs[kk] + W_], sizeof(float2));
            float s = cw[kk][0] * A.x;
            s = fmaf(cw[kk][1], A.y,  s);
            s = fmaf(cw[kk][2], Bv.x, s);
            s = fmaf(cw[kk][3], Bv.y, s);
            acc = fmaf(wp[cc * 9 + kk], s, acc);
        }
        *outp = acc + bp[cc];
        outp += HW_;

        __syncthreads();   // vmcnt(0): prefetch landed; lgkm: reads done
        pb ^= CAPE;
    }
}

extern "C" void kernel_launch(void* const* d_in, const int* in_sizes, int n_in,
                              void* d_out, int out_size, void* d_ws, size_t ws_size,
                              hipStream_t stream) {
    const float* x    = (const float*)d_in[0];
    const float* off  = (const float*)d_in[1];
    const float* w    = (const float*)d_in[2];
    const float* bias = (const float*)d_in[3];
    float* out        = (float*)d_out;
    dim3 grid(H_ / TH, B_, CSPLIT);
    deform_dw_conv<<<grid, NT, 0, stream>>>(x, off, w, bias, out);
}